// Round 16
// baseline (243.923 us; speedup 1.0000x reference)
//
#include <hip/hip_runtime.h>
#include <hip/hip_bf16.h>

typedef __attribute__((ext_vector_type(4))) float f32x4;
typedef __attribute__((ext_vector_type(16))) float f32x16;
typedef __attribute__((ext_vector_type(8))) short s16x8;
typedef __attribute__((ext_vector_type(4))) short s16x4;

#define DM 1024
#define NH 16
#define NB 2
#define NS 2048
#define NTOK (NB*NS)

__device__ __forceinline__ float b2f(short u){
  union { unsigned int i; float f; } c; c.i = ((unsigned int)(unsigned short)u) << 16; return c.f;
}
__device__ __forceinline__ short f2b(float f){
  __hip_bfloat16 h = __float2bfloat16(f);
  return __builtin_bit_cast(short, h);
}
__device__ __forceinline__ unsigned pk2(float lo, float hi){
  unsigned ul = __builtin_bit_cast(unsigned, lo);
  unsigned uh = __builtin_bit_cast(unsigned, hi);
  return (uh & 0xFFFF0000u) | (ul >> 16);
}
__device__ __forceinline__ float ex2(float x){
  float r;
  asm("v_exp_f32 %0, %1" : "=v"(r) : "v"(x));
  return r;
}
__device__ __forceinline__ float rcpf(float x){
  float r;
  asm("v_rcp_f32 %0, %1" : "=v"(r) : "v"(x));
  return r;
}
__device__ __forceinline__ void gload16(const void* g, void* l){
  __builtin_amdgcn_global_load_lds((const __attribute__((address_space(1))) void*)g,
                                   (__attribute__((address_space(3))) void*)l, 16, 0, 0);
}
__device__ __forceinline__ s16x4 tr16(const void* p){
  s16x4 r;
  asm volatile("ds_read_b64_tr_b16 %0, %1"
               : "=v"(r)
               : "v"((const __attribute__((address_space(3))) short*)p)
               : "memory");
  return r;
}

#define BARX { __builtin_amdgcn_sched_barrier(0); __builtin_amdgcn_s_barrier(); __builtin_amdgcn_sched_barrier(0); }
#define LGK  { asm volatile("s_waitcnt lgkmcnt(0)" ::: "memory"); __builtin_amdgcn_sched_barrier(0); }

// ======== 256x256 8-phase GEMM (T1+T2+T3+T4+T5), BK=64, 2 K-tiles/iter ========
template<int MIH>
__device__ __forceinline__ void rdA(s16x8 (&Af)[4][2], const short* Ab, int foff){
  #pragma unroll
  for (int m=0;m<4;m++)
    #pragma unroll
    for (int ks=0;ks<2;ks++)
      Af[m][ks] = *(const s16x8*)(Ab + (MIH*4+m)*1024 + ks*512 + foff);
}
template<int NIH>
__device__ __forceinline__ void rdB(s16x8 (&Bf)[4][2], const short* Bb, int foff){
  #pragma unroll
  for (int n=0;n<2;n++)
    #pragma unroll
    for (int ks=0;ks<2;ks++)
      Bf[NIH*2+n][ks] = *(const s16x8*)(Bb + (NIH*2+n)*1024 + ks*512 + foff);
}
template<int MIH,int NIH>
__device__ __forceinline__ void mmQ(f32x4 (&acc)[8][4], s16x8 (&Af)[4][2], s16x8 (&Bf)[4][2]){
  __builtin_amdgcn_s_setprio(1);
  #pragma unroll
  for (int m=0;m<4;m++)
    #pragma unroll
    for (int n=0;n<2;n++)
      #pragma unroll
      for (int ks=0;ks<2;ks++)
        acc[MIH*4+m][NIH*2+n] = __builtin_amdgcn_mfma_f32_16x16x32_bf16(
            Af[m][ks], Bf[NIH*2+n][ks], acc[MIH*4+m][NIH*2+n], 0,0,0);
  __builtin_amdgcn_s_setprio(0);
}

template<int GELU, int SPLITS>
__global__ __launch_bounds__(512,2) void gemm8p(
    const short* __restrict__ A, const short* __restrict__ Bt,
    const float* __restrict__ bias,
    short* __restrict__ C0, short* __restrict__ C1,
    short* __restrict__ C2, short* __restrict__ C3,
    int M, int N, int Ktot)
{
  __shared__ short Al[2*16384];
  __shared__ short Bl[2*16384];
  int tid = threadIdx.x, wid = tid>>6, lane = tid&63;
  int la = lane&15, lb = lane>>4;
  int z = blockIdx.z;
  const int Ksp = Ktot / SPLITS;
  short* C = (SPLITS==1) ? C0 : (z==0?C0 : z==1?C1 : z==2?C2 : C3);
  const short* Az  = A  + z*Ksp;
  const short* Btz = Bt + z*Ksp;
  int nbn = N>>8;
  int nwg = (M>>8)*nbn;
  int bid = (int)blockIdx.x;
  int sid = (bid&7)*(nwg>>3) + (bid>>3);
  int bm = sid / nbn, bn = sid % nbn;
  int wm2 = wid>>2, wn4 = wid&3;
  int bhalf = wn4>>1, bq4 = (wn4&1)*4;

  const short* aA0 = Az  + (size_t)(bm*256)*Ktot;
  const short* aA1 = Az  + (size_t)(bm*256+128)*Ktot;
  const short* bB0 = Btz + (size_t)(bn*256)*Ktot;
  const short* bB1 = Btz + (size_t)(bn*256+128)*Ktot;

  auto stG = [&](short* dstHalf, const short* srcRow0, int kt){
    #pragma unroll
    for (int c=0;c<2;c++){
      int s = c*8 + wid;
      int row = ((s>>1)<<4) + (lane>>2);
      int kk  = kt + ((s&1)<<5) + (((lane&3)<<3) ^ ((lane&32)>>1));
      gload16(srcRow0 + (size_t)row*Ktot + kk, dstHalf + s*512);
    }
  };

  int NJ = Ksp>>7;
  stG(&Al[0], aA0, 0);      stG(&Al[8192], aA1, 0);
  stG(&Bl[0], bB0, 0);      stG(&Bl[8192], bB1, 0);
  stG(&Bl[16384], bB0, 64); stG(&Bl[16384+8192], bB1, 64);
  asm volatile("s_waitcnt vmcnt(4)" ::: "memory");
  BARX;

  f32x4 acc[8][4] = {};
  s16x8 Af[4][2], Bf[4][2];
  int foff = la*32 + ((lb*8) ^ ((la&8)<<1));

  const short* Ab0c = &Al[wm2*8192];
  const short* Ab1c = &Al[16384 + wm2*8192];
  const short* Bb0c = &Bl[bhalf*8192 + bq4*1024];
  const short* Bb1c = &Bl[16384 + bhalf*8192 + bq4*1024];

  for (int j=0;j<NJ;j++){
    bool more = (j+1 < NJ);
    int ktA  = (2*j+1)*64;
    int ktN0 = (2*j+2)*64, ktN1 = (2*j+3)*64;
    rdA<0>(Af, Ab0c, foff); rdB<0>(Bf, Bb0c, foff);
    stG(&Al[16384], aA0, ktA);
    BARX; LGK; mmQ<0,0>(acc,Af,Bf); BARX;
    rdB<1>(Bf, Bb0c, foff);
    stG(&Al[16384+8192], aA1, ktA);
    BARX; LGK; mmQ<0,1>(acc,Af,Bf); BARX;
    rdA<1>(Af, Ab0c, foff);
    if (more) stG(&Bl[0], bB0, ktN0);
    BARX; LGK; mmQ<1,1>(acc,Af,Bf); BARX;
    if (more){ stG(&Bl[8192], bB1, ktN0);
               asm volatile("s_waitcnt vmcnt(4)" ::: "memory"); }
    else     { asm volatile("s_waitcnt vmcnt(0)" ::: "memory"); }
    BARX; mmQ<1,0>(acc,Af,Bf); BARX;
    rdA<0>(Af, Ab1c, foff); rdB<0>(Bf, Bb1c, foff);
    if (more) stG(&Al[0], aA0, ktN0);
    BARX; LGK; mmQ<0,0>(acc,Af,Bf); BARX;
    rdB<1>(Bf, Bb1c, foff);
    if (more) stG(&Al[8192], aA1, ktN0);
    BARX; LGK; mmQ<0,1>(acc,Af,Bf); BARX;
    rdA<1>(Af, Ab1c, foff);
    if (more) stG(&Bl[16384], bB0, ktN1);
    BARX; LGK; mmQ<1,1>(acc,Af,Bf); BARX;
    if (more){ stG(&Bl[16384+8192], bB1, ktN1);
               asm volatile("s_waitcnt vmcnt(4)" ::: "memory"); }
    else     { asm volatile("s_waitcnt vmcnt(0)" ::: "memory"); }
    BARX; mmQ<1,0>(acc,Af,Bf); BARX;
  }

  // ---- epilogue: bias(+GELU) -> LDS C-tile -> coalesced store ----
  short* halfC = wm2 ? Bl : Al;
  #pragma unroll
  for (int ni=0;ni<4;ni++){
    int col = wn4*64 + ni*16 + la;
    float bv = (SPLITS==1 || z==0) ? bias[bn*256 + col] : 0.0f;
    #pragma unroll
    for (int mi=0;mi<8;mi++){
      int rloc = mi*16 + lb*4;
      #pragma unroll
      for (int j=0;j<4;j++){
        float v = acc[mi][ni][j] + bv;
        if (GELU){
          float xx = v;
          float y = xx*(0.79788456f + 0.035677408f*xx*xx);
          float p = ex2(2.88539008f*y);
          v = xx - xx*rcpf(p + 1.0f);
        }
        halfC[(rloc+j)*256 + col] = f2b(v);
      }
    }
  }
  BARX;
  #pragma unroll
  for (int i=0;i<8;i++){
    int row = i*32 + (tid>>4);
    int colc = (tid&15)*16;
    const short* src = (i<4) ? &Al[(row&127)*256 + colc] : &Bl[(row&127)*256 + colc];
    s16x8 v0 = *(const s16x8*)src;
    s16x8 v1 = *(const s16x8*)(src+8);
    short* dst = &C[(size_t)(bm*256+row)*N + bn*256 + colc];
    *(s16x8*)dst = v0;
    *(s16x8*)(dst+8) = v1;
  }
}

// ---------------- Flash attention: 4-warp blocks, 4 blocks/CU, KV-split z, L2-local grid ----------------
// Grid (32 bh, 16 qt, 2 z): XCD = bh%8 -> per-head K/V L2-resident; 4 blocks/CU co-resident.
// Warp owns 32 q-rows (block 128); staging per R7's verified 4-warp mapping.
// Static softmax offset M=8 (exp2 domain, raw v_exp_f32); truncation-pack P.
__global__ __launch_bounds__(256,4) void attn_fwd(const short* __restrict__ qkv,
    short* __restrict__ Op0, short* __restrict__ Op1, float* __restrict__ ml)
{
  __shared__ short KlS[2*4096];
  __shared__ short VlS[2*4096];
  __shared__ float stats[4*32];
  char* Kl = (char*)KlS; char* Vl = (char*)VlS;
  int tid=threadIdx.x, w=tid>>6, lane=tid&63;
  int q5=lane&31, hi=lane>>5, la=lane&15, lb0=(lane>>4)&1;
  int bh=blockIdx.x, qt=blockIdx.y, z=blockIdx.z;
  int b=bh>>4, h=bh&15;
  int q0w = qt*128 + w*32;
  short* Od = z ? Op1 : Op0;
  float* Ld = ml + z*65536;

  const float QSC = 0.125f * 1.44269504f;
  const float MOFF = 8.0f;
  const short* qp = qkv + (size_t)(b*NS+q0w+q5)*3072 + h*64 + hi*8;
  s16x8 qf[4];
  #pragma unroll
  for (int ds=0; ds<4; ds++){
    s16x8 v = *(const s16x8*)(qp + ds*16);
    #pragma unroll
    for (int j=0;j<8;j++) v[j] = f2b(b2f(v[j])*QSC);
    qf[ds]=v;
  }

  const size_t tstep = (size_t)64*3072;
  // 4-warp staging: warp w covers chunks w and w+4 of K and V (1KB each)
  int krow = 8*w + (lane>>3);
  int kcolS = (((lane&7) ^ ((lane>>3)&7)) << 3);
  const short* KsrcA = qkv + (size_t)(b*NS+krow)*3072 + h*64 + 1024 + kcolS + (size_t)(z*16)*tstep;
  const short* KsrcB = KsrcA + (size_t)32*3072;
  int vk = 16*w + 8*hi + 4*lb0 + ((lane>>1)&3);
  int vd = 16*((lane>>3)&1) + 8*(lane&1);
  const short* VsrcA = qkv + (size_t)(b*NS+vk)*3072 + h*64 + 2048 + vd + (size_t)(z*16)*tstep;
  const short* VsrcB = VsrcA + 32;

  int sw = (q5&7)<<4;
  int baseK = q5*128 + ((hi<<4) ^ (sw&16)) + (sw&96);
  int baseV = hi*512 + lb0*128 + la*8;

  f32x16 cacc0={}, cacc1={};
  float lrow=0.f;

  gload16(KsrcA, Kl + w*1024);
  gload16(KsrcB, Kl + w*1024 + 4096);
  gload16(VsrcA, Vl + w*1024);
  gload16(VsrcB, Vl + w*1024 + 4096);
  __syncthreads();
  int cur=0;

  for (int t=0;t<16;t++){
    if (t+1 < 16){
      size_t o = (size_t)(t+1)*tstep;
      gload16(KsrcA + o, Kl + (cur^1)*8192 + w*1024);
      gload16(KsrcB + o, Kl + (cur^1)*8192 + w*1024 + 4096);
      gload16(VsrcA + o, Vl + (cur^1)*8192 + w*1024);
      gload16(VsrcB + o, Vl + (cur^1)*8192 + w*1024 + 4096);
    }
    const char* Kb = Kl + cur*8192;
    f32x16 s0={}, s1={};
    #pragma unroll
    for (int ds=0; ds<4; ds++){
      s16x8 k0 = *(const s16x8*)(Kb + (baseK ^ (ds<<5)));
      s16x8 k1 = *(const s16x8*)(Kb + 4096 + (baseK ^ (ds<<5)));
      s0 = __builtin_amdgcn_mfma_f32_32x32x16_bf16(k0, qf[ds], s0, 0,0,0);
      s1 = __builtin_amdgcn_mfma_f32_32x32x16_bf16(k1, qf[ds], s1, 0,0,0);
    }
    float rs = 0.f;
    #pragma unroll
    for (int r=0;r<16;r++){ float p=ex2(s0[r]-MOFF); s0[r]=p; rs+=p; }
    #pragma unroll
    for (int r=0;r<16;r++){ float p=ex2(s1[r]-MOFF); s1[r]=p; rs+=p; }
    rs += __shfl_xor(rs, 32, 64);
    lrow += rs;
    unsigned int D0[4][2], D1[4][2], R0[4][2], R1[4][2];
    #pragma unroll
    for (int bb=0;bb<4;bb++)
      #pragma unroll
      for (int hh=0;hh<2;hh++){
        D0[bb][hh] = pk2(s0[4*bb+2*hh], s0[4*bb+2*hh+1]);
        D1[bb][hh] = pk2(s1[4*bb+2*hh], s1[4*bb+2*hh+1]);
      }
    #pragma unroll
    for (int bb=0;bb<4;bb++)
      #pragma unroll
      for (int hh=0;hh<2;hh++){
        R0[bb][hh] = (unsigned int)__shfl_xor((int)D0[bb][hh], 32, 64);
        R1[bb][hh] = (unsigned int)__shfl_xor((int)D1[bb][hh], 32, 64);
      }
    union PA { unsigned int u[4]; s16x8 v; } pa[4];
    #pragma unroll
    for (int e=0;e<2;e++)
      #pragma unroll
      for (int hh=0;hh<2;hh++){
        pa[e].u[hh]     = hi ? R0[2*e+1][hh] : D0[2*e][hh];
        pa[e].u[2+hh]   = hi ? D0[2*e+1][hh] : R0[2*e][hh];
        pa[2+e].u[hh]   = hi ? R1[2*e+1][hh] : D1[2*e][hh];
        pa[2+e].u[2+hh] = hi ? D1[2*e+1][hh] : R1[2*e][hh];
      }
    const char* Vb = Vl + cur*8192;
    #pragma unroll
    for (int ks=0;ks<4;ks++){
      s16x4 t00 = tr16(Vb + ks*1024 +        0 + baseV);
      s16x4 t01 = tr16(Vb + ks*1024 +      256 + baseV);
      s16x4 t10 = tr16(Vb + ks*1024 + 4096     + baseV);
      s16x4 t11 = tr16(Vb + ks*1024 + 4096+256 + baseV);
      LGK;
      union { s16x4 hh[2]; s16x8 v; } u0, u1;
      u0.hh[0]=t00; u0.hh[1]=t01;
      u1.hh[0]=t10; u1.hh[1]=t11;
      cacc0 = __builtin_amdgcn_mfma_f32_32x32x16_bf16(pa[ks].v, u0.v, cacc0, 0,0,0);
      cacc1 = __builtin_amdgcn_mfma_f32_32x32x16_bf16(pa[ks].v, u1.v, cacc1, 0,0,0);
    }
    __syncthreads();
    cur ^= 1;
  }
  if (!hi){
    stats[w*32+q5] = 1.0f/lrow;
    Ld[bh*2048 + q0w + q5] = lrow;
  }
  LGK;
  #pragma unroll
  for (int r=0;r<16;r++){
    int q = (r&3)+8*(r>>2)+4*hi;
    float linv = stats[w*32+q];
    size_t row = (size_t)(b*NS + q0w + q)*DM + h*64;
    Od[row + q5]      = f2b(cacc0[r]*linv);
    Od[row + 32 + q5] = f2b(cacc1[r]*linv);
  }
}

// merge: ctx = (l0*O0n + l1*O1n)/(l0+l1)  (common static offset)
__global__ __launch_bounds__(256) void attn_mrg(const short* __restrict__ O0,
    const short* __restrict__ O1, const float* __restrict__ ml, short* __restrict__ ctx)
{
  int r = blockIdx.x, tid = threadIdx.x;
  int b = r>>11, q = r&2047;
  int c = tid*4;
  int h = c>>6;
  int idx = (b*16+h)*2048 + q;
  float l0 = ml[idx];
  float l1 = ml[65536+idx];
  float inv = rcpf(l0+l1);
  float w0 = l0*inv, w1 = l1*inv;
  size_t off = (size_t)r*DM + c;
  s16x4 a = *(const s16x4*)(O0+off);
  s16x4 bb = *(const s16x4*)(O1+off);
  s16x4 o;
  #pragma unroll
  for (int j=0;j<4;j++) o[j] = f2b(w0*b2f(a[j]) + w1*b2f(bb[j]));
  *(s16x4*)(ctx+off) = o;
}

// ---------------- LayerNorm helpers ----------------
__device__ __forceinline__ void wred2(float& s, float& ss){
  #pragma unroll
  for (int m=1;m<64;m<<=1){ s += __shfl_xor(s,m,64); ss += __shfl_xor(ss,m,64); }
}

// ---------------- fused prologue: 4 weight cast+transposes + ln_in ----------------
__device__ __forceinline__ void castBody(const float* __restrict__ w, short* __restrict__ wt,
                                         int R, int C, int bid, short (*t)[65], int tid)
{
  int nbr = R>>6;
  int br = bid % nbr, bc = bid / nbr;
  #pragma unroll
  for (int i=0;i<4;i++){
    int c = i*256 + tid;
    int r = c>>4, c4 = (c&15)*4;
    float4 v = *(const float4*)(w + (size_t)(br*64 + r)*C + bc*64 + c4);
    t[r][c4+0]=f2b(v.x); t[r][c4+1]=f2b(v.y); t[r][c4+2]=f2b(v.z); t[r][c4+3]=f2b(v.w);
  }
  __syncthreads();
  #pragma unroll
  for (int i=0;i<4;i++){
    int c = i*256 + tid;
    int oc = c>>4, c4 = (c&15)*4;
    s16x4 p;
    p[0]=t[c4+0][oc]; p[1]=t[c4+1][oc]; p[2]=t[c4+2][oc]; p[3]=t[c4+3][oc];
    *(s16x4*)&wt[(size_t)(bc*64 + oc)*R + br*64 + c4] = p;
  }
}

__global__ __launch_bounds__(256) void prep(
    const float* __restrict__ qkv_w, short* __restrict__ wqkvT,
    const float* __restrict__ out_w, short* __restrict__ woutT,
    const float* __restrict__ w1,    short* __restrict__ w1T,
    const float* __restrict__ w2,    short* __restrict__ w2T,
    const float* __restrict__ x, const float* __restrict__ g,
    const float* __restrict__ be, short* __restrict__ h1)
{
  __shared__ short t[64][65];
  __shared__ float r1[4], r2[4];
  int bid = blockIdx.x, tid = threadIdx.x;
  if (bid < 768){       castBody(qkv_w, wqkvT, 1024, 3072, bid, t, tid); return; }
  if (bid < 1024){      castBody(out_w, woutT, 1024, 1024, bid-768, t, tid); return; }
  if (bid < 2048){      castBody(w1, w1T, 1024, 4096, bid-1024, t, tid); return; }
  if (bid < 3072){      castBody(w2, w2T, 4096, 1024, bid-2048, t, tid); return; }
  int row = bid - 3072;
  float4 v = ((const float4*)(x + (size_t)row*DM))[tid];
  float s=v.x+v.y+v.z+v.w, ss=v.x*v.x+v.y*v.y+v.z*v.z+v.w*v.w;
  wred2(s,ss);
  if ((tid&63)==0){ r1[tid>>6]=s; r2[tid>>6]=ss; }
  __syncthreads();
  s=r1[0]+r1[1]+r1[2]+r1[3]; ss=r2[0]+r2[1]+r2[2]+r2[3];
  float mu=s*(1.f/DM);
  float rstd=rsqrtf(ss*(1.f/DM)-mu*mu+1e-5f);
  float4 gv=((const float4*)g)[tid], bv=((const float4*)be)[tid];
  s16x4 o;
  o[0]=f2b((v.x-mu)*rstd*gv.x+bv.x);
  o[1]=f2b((v.y-mu)*rstd*gv.y+bv.y);
  o[2]=f2b((v.z-mu)*rstd*gv.z+bv.z);
  o[3]=f2b((v.w-mu)*rstd*gv.w+bv.w);
  *(s16x4*)(h1 + (size_t)row*DM + tid*4) = o;
}

// x1b (bf16) = LN(x + sum partials); h2 = bf16(LN(x1))
__global__ __launch_bounds__(256) void ln_chain(const float* __restrict__ x,
    const short* __restrict__ p0, const short* __restrict__ p1,
    const short* __restrict__ p2, const short* __restrict__ p3,
    const float* __restrict__ g1, const float* __restrict__ be1,
    const float* __restrict__ g2, const float* __restrict__ be2,
    short* __restrict__ x1b, short* __restrict__ h2)
{
  int row=blockIdx.x, tid=threadIdx.x;
  __shared__ float r1[4], r2[4], r3[4], r4[4];
  size_t off = (size_t)row*DM + tid*4;
  float4 xv = ((const float4*)(x + (size_t)row*DM))[tid];
  s16x4 a0=*(const s16x4*)(p0+off), a1=*(const s16x4*)(p1+off);
  s16x4 a2=*(const s16x4*)(p2+off), a3=*(const s16x4*)(p3+off);
  float4 y;
  y.x = xv.x + b2f(a0[0])+b2f(a1[0])+b2f(a2[0])+b2f(a3[0]);
  y.y = xv.y + b2f(a0[1])+b2f(a1[1])+b2f(a2[1])+b2f(a3[1]);
  y.z = xv.z + b2f(a0[2])+b2f(a1[2])+b2f(a2[2])+b2f(a3[2]);
  y.w = xv.w + b2f(a0[3])+b2f(a1[3])+b2f(a2[3])+b2f(a3[3]);
  float s=y.x+y.y+y.z+y.w, ss=y.x*y.x+y.y*y.y+y.z*y.z+y.w*y.w;
  wred2(s,ss);
  if ((tid&63)==0){ r1[tid>>6]=s; r2[tid>>6]=ss; }
  __syncthreads();
  s=r1[0]+r1[1]+r1[2]+r1[3]; ss=r2[0]+r2[1]+r2[2]+r2[3];
  float mu=s*(1.f/DM);
  float rstd=rsqrtf(ss*(1.f/DM)-mu*mu+1e-5f);
  float4 g1v=((const float4*)g1)[tid], b1v=((const float4*)be1)[tid];
  float4 xo;
  xo.x=(y.x-mu)*rstd*g1v.x+b1v.x;
  xo.y=(y.y-mu)*rstd*g1v.y+b1v.y;
  xo.z=(y.z-mu)*rstd*g1v.z+b1v.z;
  xo.w=(y.w-mu)*rstd*g1v.w+b1v.w;
  s16x4 xb;
  xb[0]=f2b(xo.x); xb[1]=f2b(xo.y); xb[2]=f2b(xo.z); xb[3]=f2b(xo.w);
  *(s16x4*)(x1b + off) = xb;
  float s2=xo.x+xo.y+xo.z+xo.w, ss2=xo.x*xo.x+xo.y*xo.y+xo.z*xo.z+xo.w*xo.w;
  wred2(s2,ss2);
  if ((tid&63)==0){ r3[tid>>6]=s2; r4[tid>>6]=ss2; }
  __syncthreads();
  s2=r3[0]+r3[1]+r3[2]+r3[3]; ss2=r4[0]+r4[1]+r4[2]+r4[3];
  float mu2=s2*(1.f/DM);
  float rstd2=rsqrtf(ss2*(1.f/DM)-mu2*mu2+1e-5f);
  float4 g2v=((const float4*)g2)[tid], b2v=((const float4*)be2)[tid];
  s16x4 o;
  o[0]=f2b((xo.x-mu2)*rstd2*g2v.x+b2v.x);
  o[1]=f2b((xo.y-mu2)*rstd2*g2v.y+b2v.y);
  o[2]=f2b((xo.z-mu2)*rstd2*g2v.z+b2v.z);
  o[3]=f2b((xo.w-mu2)*rstd2*g2v.w+b2v.w);
  *(s16x4*)(h2 + off) = o;
}

__global__ __launch_bounds__(256) void ln_out_k(const short* __restrict__ x1b,
    const short* __restrict__ p0, const short* __restrict__ p1,
    const short* __restrict__ p2, const short* __restrict__ p3,
    const float* __restrict__ g, const float* __restrict__ be, float* __restrict__ out)
{
  int row=blockIdx.x, tid=threadIdx.x;
  __shared__ float r1[4], r2[4];
  size_t off = (size_t)row*DM + tid*4;
  s16x4 xv = *(const s16x4*)(x1b+off);
  s16x4 a0=*(const s16x4*)(p0+off), a1=*(const s16x4*)(p1+off);
  s16x4 a2=*(const s16x4*)(p2+off), a3=*(const s16x4*)(p3+off);
  float4 y;
  y.x = b2f(xv[0]) + b2f(a0[0])+b2f(a1[0])+b2f(a2[0])+b2f(a3[0]);
  y.y = b2f(xv[1]) + b2f(a0[1])+b2f(a1[1])+b2f(a2[1])+b2f(a3[1]);
  y.z = b2f(xv[2]) + b2f(a0[2])+b2f(a1[2])+b2f(a2[2])+b2f(a3[2]);
  y.w = b2f(xv[3]) + b2f(a0[3])+b2f(a1[3])+b2f(a2[3])+b2f(a3[3]);
  float s=y.x+y.y+y.z+y.w, ss=y.x*y.x+y.y*y.y+y.z*y.z+y.w*y.w;
  wred2(s,ss);
  if ((tid&63)==0){ r1[tid>>6]=s; r2[tid>>6]=ss; }
  __syncthreads();
  s=r1[0]+r1[1]+r1[2]+r1[3]; ss=r2[0]+r2[1]+r2[2]+r2[3];
  float mu=s*(1.f/DM);
  float rstd=rsqrtf(ss*(1.f/DM)-mu*mu+1e-5f);
  float4 gv=((const float4*)g)[tid], bv=((const float4*)be)[tid];
  float4 o;
  o.x=(y.x-mu)*rstd*gv.x+bv.x;
  o.y=(y.y-mu)*rstd*gv.y+bv.y;
  o.z=(y.z-mu)*rstd*gv.z+bv.z;
  o.w=(y.w-mu)*rstd*gv.w+bv.w;
  ((float4*)(out + (size_t)row*DM))[tid] = o;
}

// ---------------- launcher ----------------
extern "C" void kernel_launch(void* const* d_in, const int* in_sizes, int n_in,
                              void* d_out, int out_size, void* d_ws, size_t ws_size,
                              hipStream_t stream)
{
  const float* x      = (const float*)d_in[0];
  const float* qkv_w  = (const float*)d_in[1];
  const float* qkv_b  = (const float*)d_in[2];
  const float* out_w  = (const float*)d_in[3];
  const float* out_b  = (const float*)d_in[4];
  const float* aln_g  = (const float*)d_in[5];
  const float* aln_b  = (const float*)d_in[6];
  const float* n1_g   = (const float*)d_in[7];
  const float* n1_b   = (const float*)d_in[8];
  const float* fln_g  = (const float*)d_in[9];
  const float* fln_b  = (const float*)d_in[10];
  const float* w1     = (const float*)d_in[11];
  const float* b1     = (const float*)d_in[12];
  const float* w2     = (const float*)d_in[13];
  const float* b2     = (const float*)d_in[14];
  const float* n2_g   = (const float*)d_in[15];
  const float* n2_b   = (const float*)d_in[16];

  char* ws = (char*)d_ws;
  short* w2T   = (short*)(ws + 0);
  short* w1T   = (short*)(ws + 8388608);
  short* woutT = (short*)(ws + 16777216);
  short* wqkvT = (short*)(ws + 18874368);
  short* h1    = (short*)(ws + 25165824);
  short* qkv   = (short*)(ws + 33554432);
  short* x1b   = (short*)(ws + 67108864);
  short* ff1   = (short*)(ws + 33554432);
  short* Op1   = (short*)(ws + 25165824);
  short* Op0   = (short*)(ws + 58720256);
  float* mlb   = (float*)(ws + 18874368);
  short* ctx   = (short*)(ws + 33554432);
  short* Po0 = (short*)(ws + 25165824);
  short* Po1 = (short*)(ws + 41943040);
  short* Po2 = (short*)(ws + 50331648);
  short* Po3 = (short*)(ws + 58720256);
  short* Pf0 = (short*)(ws + 8388608);
  short* Pf1 = (short*)(ws + 16777216);
  short* Pf2 = (short*)(ws + 25165824);
  short* Pf3 = (short*)(ws + 83886080);
  float* outp  = (float*)d_out;

  prep<<<dim3(3072+NTOK),256,0,stream>>>(qkv_w,wqkvT, out_w,woutT, w1,w1T, w2,w2T,
                                         x, aln_g, aln_b, h1);
  gemm8p<0,1><<<dim3(192,1,1),512,0,stream>>>(h1, wqkvT, qkv_b, qkv,qkv,qkv,qkv, 4096,3072,1024);
  attn_fwd<<<dim3(32,16,2),256,0,stream>>>(qkv, Op0, Op1, mlb);
  attn_mrg<<<dim3(4096),256,0,stream>>>(Op0, Op1, mlb, ctx);
  gemm8p<0,4><<<dim3(64,1,4),512,0,stream>>>(ctx, woutT, out_b, Po0,Po1,Po2,Po3, 4096,1024,1024);
  ln_chain<<<NTOK,256,0,stream>>>(x, Po0,Po1,Po2,Po3, n1_g,n1_b, fln_g,fln_b, x1b, h1);
  gemm8p<1,1><<<dim3(256,1,1),512,0,stream>>>(h1, w1T, b1, ff1,ff1,ff1,ff1, 4096,4096,1024);
  gemm8p<0,4><<<dim3(64,1,4),512,0,stream>>>(ff1, w2T, b2, Pf0,Pf1,Pf2,Pf3, 4096,1024,4096);
  ln_out_k<<<NTOK,256,0,stream>>>(x1b, Pf0,Pf1,Pf2,Pf3, n2_g,n2_b, outp);
}

// Round 17
// 240.084 us; speedup vs baseline: 1.0160x; 1.0160x over previous
//
#include <hip/hip_runtime.h>
#include <hip/hip_bf16.h>

typedef __attribute__((ext_vector_type(4))) float f32x4;
typedef __attribute__((ext_vector_type(16))) float f32x16;
typedef __attribute__((ext_vector_type(8))) short s16x8;
typedef __attribute__((ext_vector_type(4))) short s16x4;

#define DM 1024
#define NH 16
#define NB 2
#define NS 2048
#define NTOK (NB*NS)

__device__ __forceinline__ float b2f(short u){
  union { unsigned int i; float f; } c; c.i = ((unsigned int)(unsigned short)u) << 16; return c.f;
}
__device__ __forceinline__ short f2b(float f){
  __hip_bfloat16 h = __float2bfloat16(f);
  return __builtin_bit_cast(short, h);
}
__device__ __forceinline__ unsigned pk2(float lo, float hi){
  unsigned ul = __builtin_bit_cast(unsigned, lo);
  unsigned uh = __builtin_bit_cast(unsigned, hi);
  return (uh & 0xFFFF0000u) | (ul >> 16);
}
__device__ __forceinline__ float ex2(float x){
  float r;
  asm("v_exp_f32 %0, %1" : "=v"(r) : "v"(x));
  return r;
}
__device__ __forceinline__ float rcpf(float x){
  float r;
  asm("v_rcp_f32 %0, %1" : "=v"(r) : "v"(x));
  return r;
}
__device__ __forceinline__ void gload16(const void* g, void* l){
  __builtin_amdgcn_global_load_lds((const __attribute__((address_space(1))) void*)g,
                                   (__attribute__((address_space(3))) void*)l, 16, 0, 0);
}
__device__ __forceinline__ s16x4 tr16(const void* p){
  s16x4 r;
  asm volatile("ds_read_b64_tr_b16 %0, %1"
               : "=v"(r)
               : "v"((const __attribute__((address_space(3))) short*)p)
               : "memory");
  return r;
}

#define BARX { __builtin_amdgcn_sched_barrier(0); __builtin_amdgcn_s_barrier(); __builtin_amdgcn_sched_barrier(0); }
#define LGK  { asm volatile("s_waitcnt lgkmcnt(0)" ::: "memory"); __builtin_amdgcn_sched_barrier(0); }

// ======== 256x256 8-phase GEMM (T1+T2+T3+T4+T5), BK=64, 2 K-tiles/iter ========
template<int MIH>
__device__ __forceinline__ void rdA(s16x8 (&Af)[4][2], const short* Ab, int foff){
  #pragma unroll
  for (int m=0;m<4;m++)
    #pragma unroll
    for (int ks=0;ks<2;ks++)
      Af[m][ks] = *(const s16x8*)(Ab + (MIH*4+m)*1024 + ks*512 + foff);
}
template<int NIH>
__device__ __forceinline__ void rdB(s16x8 (&Bf)[4][2], const short* Bb, int foff){
  #pragma unroll
  for (int n=0;n<2;n++)
    #pragma unroll
    for (int ks=0;ks<2;ks++)
      Bf[NIH*2+n][ks] = *(const s16x8*)(Bb + (NIH*2+n)*1024 + ks*512 + foff);
}
template<int MIH,int NIH>
__device__ __forceinline__ void mmQ(f32x4 (&acc)[8][4], s16x8 (&Af)[4][2], s16x8 (&Bf)[4][2]){
  __builtin_amdgcn_s_setprio(1);
  #pragma unroll
  for (int m=0;m<4;m++)
    #pragma unroll
    for (int n=0;n<2;n++)
      #pragma unroll
      for (int ks=0;ks<2;ks++)
        acc[MIH*4+m][NIH*2+n] = __builtin_amdgcn_mfma_f32_16x16x32_bf16(
            Af[m][ks], Bf[NIH*2+n][ks], acc[MIH*4+m][NIH*2+n], 0,0,0);
  __builtin_amdgcn_s_setprio(0);
}

template<int GELU, int SPLITS>
__global__ __launch_bounds__(512,2) void gemm8p(
    const short* __restrict__ A, const short* __restrict__ Bt,
    const float* __restrict__ bias,
    short* __restrict__ C0, short* __restrict__ C1,
    short* __restrict__ C2, short* __restrict__ C3,
    int M, int N, int Ktot)
{
  __shared__ short Al[2*16384];
  __shared__ short Bl[2*16384];
  int tid = threadIdx.x, wid = tid>>6, lane = tid&63;
  int la = lane&15, lb = lane>>4;
  int z = blockIdx.z;
  const int Ksp = Ktot / SPLITS;
  short* C = (SPLITS==1) ? C0 : (z==0?C0 : z==1?C1 : z==2?C2 : C3);
  const short* Az  = A  + z*Ksp;
  const short* Btz = Bt + z*Ksp;
  int nbn = N>>8;
  int nwg = (M>>8)*nbn;
  int bid = (int)blockIdx.x;
  int sid = (bid&7)*(nwg>>3) + (bid>>3);
  int bm = sid / nbn, bn = sid % nbn;
  int wm2 = wid>>2, wn4 = wid&3;
  int bhalf = wn4>>1, bq4 = (wn4&1)*4;

  const short* aA0 = Az  + (size_t)(bm*256)*Ktot;
  const short* aA1 = Az  + (size_t)(bm*256+128)*Ktot;
  const short* bB0 = Btz + (size_t)(bn*256)*Ktot;
  const short* bB1 = Btz + (size_t)(bn*256+128)*Ktot;

  auto stG = [&](short* dstHalf, const short* srcRow0, int kt){
    #pragma unroll
    for (int c=0;c<2;c++){
      int s = c*8 + wid;
      int row = ((s>>1)<<4) + (lane>>2);
      int kk  = kt + ((s&1)<<5) + (((lane&3)<<3) ^ ((lane&32)>>1));
      gload16(srcRow0 + (size_t)row*Ktot + kk, dstHalf + s*512);
    }
  };

  int NJ = Ksp>>7;
  stG(&Al[0], aA0, 0);      stG(&Al[8192], aA1, 0);
  stG(&Bl[0], bB0, 0);      stG(&Bl[8192], bB1, 0);
  stG(&Bl[16384], bB0, 64); stG(&Bl[16384+8192], bB1, 64);
  asm volatile("s_waitcnt vmcnt(4)" ::: "memory");
  BARX;

  f32x4 acc[8][4] = {};
  s16x8 Af[4][2], Bf[4][2];
  int foff = la*32 + ((lb*8) ^ ((la&8)<<1));

  const short* Ab0c = &Al[wm2*8192];
  const short* Ab1c = &Al[16384 + wm2*8192];
  const short* Bb0c = &Bl[bhalf*8192 + bq4*1024];
  const short* Bb1c = &Bl[16384 + bhalf*8192 + bq4*1024];

  for (int j=0;j<NJ;j++){
    bool more = (j+1 < NJ);
    int ktA  = (2*j+1)*64;
    int ktN0 = (2*j+2)*64, ktN1 = (2*j+3)*64;
    rdA<0>(Af, Ab0c, foff); rdB<0>(Bf, Bb0c, foff);
    stG(&Al[16384], aA0, ktA);
    BARX; LGK; mmQ<0,0>(acc,Af,Bf); BARX;
    rdB<1>(Bf, Bb0c, foff);
    stG(&Al[16384+8192], aA1, ktA);
    BARX; LGK; mmQ<0,1>(acc,Af,Bf); BARX;
    rdA<1>(Af, Ab0c, foff);
    if (more) stG(&Bl[0], bB0, ktN0);
    BARX; LGK; mmQ<1,1>(acc,Af,Bf); BARX;
    if (more){ stG(&Bl[8192], bB1, ktN0);
               asm volatile("s_waitcnt vmcnt(4)" ::: "memory"); }
    else     { asm volatile("s_waitcnt vmcnt(0)" ::: "memory"); }
    BARX; mmQ<1,0>(acc,Af,Bf); BARX;
    rdA<0>(Af, Ab1c, foff); rdB<0>(Bf, Bb1c, foff);
    if (more) stG(&Al[0], aA0, ktN0);
    BARX; LGK; mmQ<0,0>(acc,Af,Bf); BARX;
    rdB<1>(Bf, Bb1c, foff);
    if (more) stG(&Al[8192], aA1, ktN0);
    BARX; LGK; mmQ<0,1>(acc,Af,Bf); BARX;
    rdA<1>(Af, Ab1c, foff);
    if (more) stG(&Bl[16384], bB0, ktN1);
    BARX; LGK; mmQ<1,1>(acc,Af,Bf); BARX;
    if (more){ stG(&Bl[16384+8192], bB1, ktN1);
               asm volatile("s_waitcnt vmcnt(4)" ::: "memory"); }
    else     { asm volatile("s_waitcnt vmcnt(0)" ::: "memory"); }
    BARX; mmQ<1,0>(acc,Af,Bf); BARX;
  }

  // ---- epilogue: bias(+GELU) -> LDS C-tile -> coalesced store ----
  short* halfC = wm2 ? Bl : Al;
  #pragma unroll
  for (int ni=0;ni<4;ni++){
    int col = wn4*64 + ni*16 + la;
    float bv = (SPLITS==1 || z==0) ? bias[bn*256 + col] : 0.0f;
    #pragma unroll
    for (int mi=0;mi<8;mi++){
      int rloc = mi*16 + lb*4;
      #pragma unroll
      for (int j=0;j<4;j++){
        float v = acc[mi][ni][j] + bv;
        if (GELU){
          float xx = v;
          float y = xx*(0.79788456f + 0.035677408f*xx*xx);
          float p = ex2(2.88539008f*y);
          v = xx - xx*rcpf(p + 1.0f);
        }
        halfC[(rloc+j)*256 + col] = f2b(v);
      }
    }
  }
  BARX;
  #pragma unroll
  for (int i=0;i<8;i++){
    int row = i*32 + (tid>>4);
    int colc = (tid&15)*16;
    const short* src = (i<4) ? &Al[(row&127)*256 + colc] : &Bl[(row&127)*256 + colc];
    s16x8 v0 = *(const s16x8*)src;
    s16x8 v1 = *(const s16x8*)(src+8);
    short* dst = &C[(size_t)(bm*256+row)*N + bn*256 + colc];
    *(s16x8*)dst = v0;
    *(s16x8*)(dst+8) = v1;
  }
}

// ---------------- Flash attention, 8-warp 32x32 swapped-QK, KV-split z in {0,1} ----------------
// Grid (32 bh, 8 qt, 2 z): XCD = bh%8 -> per-head K/V L2-resident (R15-proven, FETCH 12MB).
// Static softmax offset M=8 (exp2 domain, raw v_exp_f32); truncation-pack P.
__global__ __launch_bounds__(512,2) void attn_fwd(const short* __restrict__ qkv,
    short* __restrict__ Op0, short* __restrict__ Op1, float* __restrict__ ml)
{
  __shared__ short KlS[2*4096];
  __shared__ short VlS[2*4096];
  __shared__ float stats[8*32];
  char* Kl = (char*)KlS; char* Vl = (char*)VlS;
  int tid=threadIdx.x, w=tid>>6, lane=tid&63;
  int q5=lane&31, hi=lane>>5, la=lane&15, lb0=(lane>>4)&1;
  int bh=blockIdx.x, qt=blockIdx.y, z=blockIdx.z;
  int b=bh>>4, h=bh&15;
  int q0w = qt*256 + w*32;
  short* Od = z ? Op1 : Op0;
  float* Ld = ml + z*65536;

  const float QSC = 0.125f * 1.44269504f;
  const float MOFF = 8.0f;
  const short* qp = qkv + (size_t)(b*NS+q0w+q5)*3072 + h*64 + hi*8;
  s16x8 qf[4];
  #pragma unroll
  for (int ds=0; ds<4; ds++){
    s16x8 v = *(const s16x8*)(qp + ds*16);
    #pragma unroll
    for (int j=0;j<8;j++) v[j] = f2b(b2f(v[j])*QSC);
    qf[ds]=v;
  }

  const size_t tstep = (size_t)64*3072;
  int krow = 8*w + (lane>>3);
  int kcolS = (((lane&7) ^ ((lane>>3)&7)) << 3);
  const short* Ksrc = qkv + (size_t)(b*NS+krow)*3072 + h*64 + 1024 + kcolS + (size_t)(z*16)*tstep;
  int vk = 16*(w&3) + 8*hi + 4*lb0 + ((lane>>1)&3);
  int vd = 32*(w>>2) + 16*((lane>>3)&1) + 8*(lane&1);
  const short* Vsrc = qkv + (size_t)(b*NS+vk)*3072 + h*64 + 2048 + vd + (size_t)(z*16)*tstep;

  int sw = (q5&7)<<4;
  int baseK = q5*128 + ((hi<<4) ^ (sw&16)) + (sw&96);
  int baseV = hi*512 + lb0*128 + la*8;

  f32x16 cacc0={}, cacc1={};
  float lrow=0.f;

  gload16(Ksrc, Kl + w*1024);
  gload16(Vsrc, Vl + w*1024);
  __syncthreads();
  int cur=0;

  for (int t=0;t<16;t++){
    if (t+1 < 16){
      gload16(Ksrc + (size_t)(t+1)*tstep, Kl + (cur^1)*8192 + w*1024);
      gload16(Vsrc + (size_t)(t+1)*tstep, Vl + (cur^1)*8192 + w*1024);
    }
    const char* Kb = Kl + cur*8192;
    f32x16 s0={}, s1={};
    #pragma unroll
    for (int ds=0; ds<4; ds++){
      s16x8 k0 = *(const s16x8*)(Kb + (baseK ^ (ds<<5)));
      s16x8 k1 = *(const s16x8*)(Kb + 4096 + (baseK ^ (ds<<5)));
      s0 = __builtin_amdgcn_mfma_f32_32x32x16_bf16(k0, qf[ds], s0, 0,0,0);
      s1 = __builtin_amdgcn_mfma_f32_32x32x16_bf16(k1, qf[ds], s1, 0,0,0);
    }
    float rs = 0.f;
    #pragma unroll
    for (int r=0;r<16;r++){ float p=ex2(s0[r]-MOFF); s0[r]=p; rs+=p; }
    #pragma unroll
    for (int r=0;r<16;r++){ float p=ex2(s1[r]-MOFF); s1[r]=p; rs+=p; }
    rs += __shfl_xor(rs, 32, 64);
    lrow += rs;
    unsigned int D0[4][2], D1[4][2], R0[4][2], R1[4][2];
    #pragma unroll
    for (int bb=0;bb<4;bb++)
      #pragma unroll
      for (int hh=0;hh<2;hh++){
        D0[bb][hh] = pk2(s0[4*bb+2*hh], s0[4*bb+2*hh+1]);
        D1[bb][hh] = pk2(s1[4*bb+2*hh], s1[4*bb+2*hh+1]);
      }
    #pragma unroll
    for (int bb=0;bb<4;bb++)
      #pragma unroll
      for (int hh=0;hh<2;hh++){
        R0[bb][hh] = (unsigned int)__shfl_xor((int)D0[bb][hh], 32, 64);
        R1[bb][hh] = (unsigned int)__shfl_xor((int)D1[bb][hh], 32, 64);
      }
    union PA { unsigned int u[4]; s16x8 v; } pa[4];
    #pragma unroll
    for (int e=0;e<2;e++)
      #pragma unroll
      for (int hh=0;hh<2;hh++){
        pa[e].u[hh]     = hi ? R0[2*e+1][hh] : D0[2*e][hh];
        pa[e].u[2+hh]   = hi ? D0[2*e+1][hh] : R0[2*e][hh];
        pa[2+e].u[hh]   = hi ? R1[2*e+1][hh] : D1[2*e][hh];
        pa[2+e].u[2+hh] = hi ? D1[2*e+1][hh] : R1[2*e][hh];
      }
    const char* Vb = Vl + cur*8192;
    #pragma unroll
    for (int ks=0;ks<4;ks++){
      s16x4 t00 = tr16(Vb + ks*1024 +        0 + baseV);
      s16x4 t01 = tr16(Vb + ks*1024 +      256 + baseV);
      s16x4 t10 = tr16(Vb + ks*1024 + 4096     + baseV);
      s16x4 t11 = tr16(Vb + ks*1024 + 4096+256 + baseV);
      LGK;
      union { s16x4 hh[2]; s16x8 v; } u0, u1;
      u0.hh[0]=t00; u0.hh[1]=t01;
      u1.hh[0]=t10; u1.hh[1]=t11;
      cacc0 = __builtin_amdgcn_mfma_f32_32x32x16_bf16(pa[ks].v, u0.v, cacc0, 0,0,0);
      cacc1 = __builtin_amdgcn_mfma_f32_32x32x16_bf16(pa[ks].v, u1.v, cacc1, 0,0,0);
    }
    __syncthreads();
    cur ^= 1;
  }
  if (!hi){
    stats[w*32+q5] = 1.0f/lrow;
    Ld[bh*2048 + q0w + q5] = lrow;
  }
  LGK;
  #pragma unroll
  for (int r=0;r<16;r++){
    int q = (r&3)+8*(r>>2)+4*hi;
    float linv = stats[w*32+q];
    size_t row = (size_t)(b*NS + q0w + q)*DM + h*64;
    Od[row + q5]      = f2b(cacc0[r]*linv);
    Od[row + 32 + q5] = f2b(cacc1[r]*linv);
  }
}

// merge: ctx = (l0*O0n + l1*O1n)/(l0+l1)  (common static offset); 8 elems/thread
__global__ __launch_bounds__(256) void attn_mrg(const short* __restrict__ O0,
    const short* __restrict__ O1, const float* __restrict__ ml, short* __restrict__ ctx)
{
  int blk = blockIdx.x, tid = threadIdx.x;
  int r = blk*2 + (tid>>7);          // token row (2 rows per block)
  int b = r>>11, q = r&2047;
  int c = (tid&127)*8;
  int h = c>>6;
  int idx = (b*16+h)*2048 + q;
  float l0 = ml[idx];
  float l1 = ml[65536+idx];
  float inv = rcpf(l0+l1);
  float w0 = l0*inv, w1 = l1*inv;
  size_t off = (size_t)r*DM + c;
  s16x8 a = *(const s16x8*)(O0+off);
  s16x8 bb = *(const s16x8*)(O1+off);
  s16x8 o;
  #pragma unroll
  for (int j=0;j<8;j++) o[j] = f2b(w0*b2f(a[j]) + w1*b2f(bb[j]));
  *(s16x8*)(ctx+off) = o;
}

// ---------------- LayerNorm helpers ----------------
__device__ __forceinline__ void wred2(float& s, float& ss){
  #pragma unroll
  for (int m=1;m<64;m<<=1){ s += __shfl_xor(s,m,64); ss += __shfl_xor(ss,m,64); }
}

// ---------------- fused prologue: 4 weight cast+transposes + ln_in ----------------
__device__ __forceinline__ void castBody(const float* __restrict__ w, short* __restrict__ wt,
                                         int R, int C, int bid, short (*t)[65], int tid)
{
  int nbr = R>>6;
  int br = bid % nbr, bc = bid / nbr;
  #pragma unroll
  for (int i=0;i<4;i++){
    int c = i*256 + tid;
    int r = c>>4, c4 = (c&15)*4;
    float4 v = *(const float4*)(w + (size_t)(br*64 + r)*C + bc*64 + c4);
    t[r][c4+0]=f2b(v.x); t[r][c4+1]=f2b(v.y); t[r][c4+2]=f2b(v.z); t[r][c4+3]=f2b(v.w);
  }
  __syncthreads();
  #pragma unroll
  for (int i=0;i<4;i++){
    int c = i*256 + tid;
    int oc = c>>4, c4 = (c&15)*4;
    s16x4 p;
    p[0]=t[c4+0][oc]; p[1]=t[c4+1][oc]; p[2]=t[c4+2][oc]; p[3]=t[c4+3][oc];
    *(s16x4*)&wt[(size_t)(bc*64 + oc)*R + br*64 + c4] = p;
  }
}

__global__ __launch_bounds__(256) void prep(
    const float* __restrict__ qkv_w, short* __restrict__ wqkvT,
    const float* __restrict__ out_w, short* __restrict__ woutT,
    const float* __restrict__ w1,    short* __restrict__ w1T,
    const float* __restrict__ w2,    short* __restrict__ w2T,
    const float* __restrict__ x, const float* __restrict__ g,
    const float* __restrict__ be, short* __restrict__ h1)
{
  __shared__ short t[64][65];
  __shared__ float r1[4], r2[4];
  int bid = blockIdx.x, tid = threadIdx.x;
  if (bid < 768){       castBody(qkv_w, wqkvT, 1024, 3072, bid, t, tid); return; }
  if (bid < 1024){      castBody(out_w, woutT, 1024, 1024, bid-768, t, tid); return; }
  if (bid < 2048){      castBody(w1, w1T, 1024, 4096, bid-1024, t, tid); return; }
  if (bid < 3072){      castBody(w2, w2T, 4096, 1024, bid-2048, t, tid); return; }
  int row = bid - 3072;
  float4 v = ((const float4*)(x + (size_t)row*DM))[tid];
  float s=v.x+v.y+v.z+v.w, ss=v.x*v.x+v.y*v.y+v.z*v.z+v.w*v.w;
  wred2(s,ss);
  if ((tid&63)==0){ r1[tid>>6]=s; r2[tid>>6]=ss; }
  __syncthreads();
  s=r1[0]+r1[1]+r1[2]+r1[3]; ss=r2[0]+r2[1]+r2[2]+r2[3];
  float mu=s*(1.f/DM);
  float rstd=rsqrtf(ss*(1.f/DM)-mu*mu+1e-5f);
  float4 gv=((const float4*)g)[tid], bv=((const float4*)be)[tid];
  s16x4 o;
  o[0]=f2b((v.x-mu)*rstd*gv.x+bv.x);
  o[1]=f2b((v.y-mu)*rstd*gv.y+bv.y);
  o[2]=f2b((v.z-mu)*rstd*gv.z+bv.z);
  o[3]=f2b((v.w-mu)*rstd*gv.w+bv.w);
  *(s16x4*)(h1 + (size_t)row*DM + tid*4) = o;
}

// x1b (bf16) = LN(x + sum partials); h2 = bf16(LN(x1))
__global__ __launch_bounds__(256) void ln_chain(const float* __restrict__ x,
    const short* __restrict__ p0, const short* __restrict__ p1,
    const short* __restrict__ p2, const short* __restrict__ p3,
    const float* __restrict__ g1, const float* __restrict__ be1,
    const float* __restrict__ g2, const float* __restrict__ be2,
    short* __restrict__ x1b, short* __restrict__ h2)
{
  int row=blockIdx.x, tid=threadIdx.x;
  __shared__ float r1[4], r2[4], r3[4], r4[4];
  size_t off = (size_t)row*DM + tid*4;
  float4 xv = ((const float4*)(x + (size_t)row*DM))[tid];
  s16x4 a0=*(const s16x4*)(p0+off), a1=*(const s16x4*)(p1+off);
  s16x4 a2=*(const s16x4*)(p2+off), a3=*(const s16x4*)(p3+off);
  float4 y;
  y.x = xv.x + b2f(a0[0])+b2f(a1[0])+b2f(a2[0])+b2f(a3[0]);
  y.y = xv.y + b2f(a0[1])+b2f(a1[1])+b2f(a2[1])+b2f(a3[1]);
  y.z = xv.z + b2f(a0[2])+b2f(a1[2])+b2f(a2[2])+b2f(a3[2]);
  y.w = xv.w + b2f(a0[3])+b2f(a1[3])+b2f(a2[3])+b2f(a3[3]);
  float s=y.x+y.y+y.z+y.w, ss=y.x*y.x+y.y*y.y+y.z*y.z+y.w*y.w;
  wred2(s,ss);
  if ((tid&63)==0){ r1[tid>>6]=s; r2[tid>>6]=ss; }
  __syncthreads();
  s=r1[0]+r1[1]+r1[2]+r1[3]; ss=r2[0]+r2[1]+r2[2]+r2[3];
  float mu=s*(1.f/DM);
  float rstd=rsqrtf(ss*(1.f/DM)-mu*mu+1e-5f);
  float4 g1v=((const float4*)g1)[tid], b1v=((const float4*)be1)[tid];
  float4 xo;
  xo.x=(y.x-mu)*rstd*g1v.x+b1v.x;
  xo.y=(y.y-mu)*rstd*g1v.y+b1v.y;
  xo.z=(y.z-mu)*rstd*g1v.z+b1v.z;
  xo.w=(y.w-mu)*rstd*g1v.w+b1v.w;
  s16x4 xb;
  xb[0]=f2b(xo.x); xb[1]=f2b(xo.y); xb[2]=f2b(xo.z); xb[3]=f2b(xo.w);
  *(s16x4*)(x1b + off) = xb;
  float s2=xo.x+xo.y+xo.z+xo.w, ss2=xo.x*xo.x+xo.y*xo.y+xo.z*xo.z+xo.w*xo.w;
  wred2(s2,ss2);
  if ((tid&63)==0){ r3[tid>>6]=s2; r4[tid>>6]=ss2; }
  __syncthreads();
  s2=r3[0]+r3[1]+r3[2]+r3[3]; ss2=r4[0]+r4[1]+r4[2]+r4[3];
  float mu2=s2*(1.f/DM);
  float rstd2=rsqrtf(ss2*(1.f/DM)-mu2*mu2+1e-5f);
  float4 g2v=((const float4*)g2)[tid], b2v=((const float4*)be2)[tid];
  s16x4 o;
  o[0]=f2b((xo.x-mu2)*rstd2*g2v.x+b2v.x);
  o[1]=f2b((xo.y-mu2)*rstd2*g2v.y+b2v.y);
  o[2]=f2b((xo.z-mu2)*rstd2*g2v.z+b2v.z);
  o[3]=f2b((xo.w-mu2)*rstd2*g2v.w+b2v.w);
  *(s16x4*)(h2 + off) = o;
}

__global__ __launch_bounds__(256) void ln_out_k(const short* __restrict__ x1b,
    const short* __restrict__ p0, const short* __restrict__ p1,
    const short* __restrict__ p2, const short* __restrict__ p3,
    const float* __restrict__ g, const float* __restrict__ be, float* __restrict__ out)
{
  int row=blockIdx.x, tid=threadIdx.x;
  __shared__ float r1[4], r2[4];
  size_t off = (size_t)row*DM + tid*4;
  s16x4 xv = *(const s16x4*)(x1b+off);
  s16x4 a0=*(const s16x4*)(p0+off), a1=*(const s16x4*)(p1+off);
  s16x4 a2=*(const s16x4*)(p2+off), a3=*(const s16x4*)(p3+off);
  float4 y;
  y.x = b2f(xv[0]) + b2f(a0[0])+b2f(a1[0])+b2f(a2[0])+b2f(a3[0]);
  y.y = b2f(xv[1]) + b2f(a0[1])+b2f(a1[1])+b2f(a2[1])+b2f(a3[1]);
  y.z = b2f(xv[2]) + b2f(a0[2])+b2f(a1[2])+b2f(a2[2])+b2f(a3[2]);
  y.w = b2f(xv[3]) + b2f(a0[3])+b2f(a1[3])+b2f(a2[3])+b2f(a3[3]);
  float s=y.x+y.y+y.z+y.w, ss=y.x*y.x+y.y*y.y+y.z*y.z+y.w*y.w;
  wred2(s,ss);
  if ((tid&63)==0){ r1[tid>>6]=s; r2[tid>>6]=ss; }
  __syncthreads();
  s=r1[0]+r1[1]+r1[2]+r1[3]; ss=r2[0]+r2[1]+r2[2]+r2[3];
  float mu=s*(1.f/DM);
  float rstd=rsqrtf(ss*(1.f/DM)-mu*mu+1e-5f);
  float4 gv=((const float4*)g)[tid], bv=((const float4*)be)[tid];
  float4 o;
  o.x=(y.x-mu)*rstd*gv.x+bv.x;
  o.y=(y.y-mu)*rstd*gv.y+bv.y;
  o.z=(y.z-mu)*rstd*gv.z+bv.z;
  o.w=(y.w-mu)*rstd*gv.w+bv.w;
  ((float4*)(out + (size_t)row*DM))[tid] = o;
}

// ---------------- launcher ----------------
extern "C" void kernel_launch(void* const* d_in, const int* in_sizes, int n_in,
                              void* d_out, int out_size, void* d_ws, size_t ws_size,
                              hipStream_t stream)
{
  const float* x      = (const float*)d_in[0];
  const float* qkv_w  = (const float*)d_in[1];
  const float* qkv_b  = (const float*)d_in[2];
  const float* out_w  = (const float*)d_in[3];
  const float* out_b  = (const float*)d_in[4];
  const float* aln_g  = (const float*)d_in[5];
  const float* aln_b  = (const float*)d_in[6];
  const float* n1_g   = (const float*)d_in[7];
  const float* n1_b   = (const float*)d_in[8];
  const float* fln_g  = (const float*)d_in[9];
  const float* fln_b  = (const float*)d_in[10];
  const float* w1     = (const float*)d_in[11];
  const float* b1     = (const float*)d_in[12];
  const float* w2     = (const float*)d_in[13];
  const float* b2     = (const float*)d_in[14];
  const float* n2_g   = (const float*)d_in[15];
  const float* n2_b   = (const float*)d_in[16];

  char* ws = (char*)d_ws;
  short* w2T   = (short*)(ws + 0);
  short* w1T   = (short*)(ws + 8388608);
  short* woutT = (short*)(ws + 16777216);
  short* wqkvT = (short*)(ws + 18874368);
  short* h1    = (short*)(ws + 25165824);
  short* qkv   = (short*)(ws + 33554432);
  short* x1b   = (short*)(ws + 67108864);
  short* ff1   = (short*)(ws + 33554432);
  short* Op1   = (short*)(ws + 25165824);
  short* Op0   = (short*)(ws + 58720256);
  float* mlb   = (float*)(ws + 18874368);
  short* ctx   = (short*)(ws + 33554432);
  short* Po0 = (short*)(ws + 25165824);
  short* Po1 = (short*)(ws + 41943040);
  short* Po2 = (short*)(ws + 50331648);
  short* Po3 = (short*)(ws + 58720256);
  short* Pf0 = (short*)(ws + 8388608);
  short* Pf1 = (short*)(ws + 16777216);
  short* Pf2 = (short*)(ws + 25165824);
  short* Pf3 = (short*)(ws + 83886080);
  float* outp  = (float*)d_out;

  prep<<<dim3(3072+NTOK),256,0,stream>>>(qkv_w,wqkvT, out_w,woutT, w1,w1T, w2,w2T,
                                         x, aln_g, aln_b, h1);
  gemm8p<0,1><<<dim3(192,1,1),512,0,stream>>>(h1, wqkvT, qkv_b, qkv,qkv,qkv,qkv, 4096,3072,1024);
  attn_fwd<<<dim3(32,8,2),512,0,stream>>>(qkv, Op0, Op1, mlb);
  attn_mrg<<<dim3(2048),256,0,stream>>>(Op0, Op1, mlb, ctx);
  gemm8p<0,4><<<dim3(64,1,4),512,0,stream>>>(ctx, woutT, out_b, Po0,Po1,Po2,Po3, 4096,1024,1024);
  ln_chain<<<NTOK,256,0,stream>>>(x, Po0,Po1,Po2,Po3, n1_g,n1_b, fln_g,fln_b, x1b, h1);
  gemm8p<1,1><<<dim3(256,1,1),512,0,stream>>>(h1, w1T, b1, ff1,ff1,ff1,ff1, 4096,4096,1024);
  gemm8p<0,4><<<dim3(64,1,4),512,0,stream>>>(ff1, w2T, b2, Pf0,Pf1,Pf2,Pf3, 4096,1024,4096);
  ln_out_k<<<NTOK,256,0,stream>>>(x1b, Pf0,Pf1,Pf2,Pf3, n2_g,n2_b, outp);
}